// Round 10
// baseline (261.908 us; speedup 1.0000x reference)
//
#include <hip/hip_runtime.h>
#include <math.h>

#define B_ 32
#define C_ 40000
#define D_ 2048
#define T_SCALE 10.0f
#define P_MARG 0.2f
#define N_MARG 0.3f
#define NWAVE (C_ / 16)  // 2500 col-groups of 16 (PM/PS stride)
#define NBLK2 (C_ / 32)  // 1250 blocks (2 waves each)
#define NSTEP (D_ / 32)  // 64 k-steps of K=32

typedef __attribute__((ext_vector_type(4))) float f32x4;
typedef __fp16 fp16x2 __attribute__((ext_vector_type(2)));
typedef _Float16 half8_t __attribute__((ext_vector_type(8)));

// async global->LDS, 16B per lane; LDS dest = wave-uniform base + lane*16
#define GLL(gsrc, ldst)                                                          \
    __builtin_amdgcn_global_load_lds(                                            \
        (const __attribute__((address_space(1))) unsigned int*)(gsrc),           \
        (__attribute__((address_space(3))) unsigned int*)(ldst), 16, 0, 0)

// ---- workspace layout (in floats) ----
#define PM_OFF 0                      // pmax [32][NWAVE]
#define PM_FLOATS (B_ * NWAVE)
#define PS_OFF (PM_OFF + PM_FLOATS)   // psum [32][NWAVE]
#define PS_FLOATS (B_ * NWAVE)
#define SC_OFF (PS_OFF + PS_FLOATS)   // scalars
#define S_HLOSS 0
#define S_THSUM 1
#define S_THCNT 2
#define S_BAD 3
#define S_NTH 4  // 32 floats
#define S_BU 36  // 32 floats
#define SC_FLOATS 128
#define DT_OFF (SC_OFF + SC_FLOATS)   // raw batch dots [32][32]
#define DT_FLOATS (32 * 32)
#define AF_OFF (DT_OFF + DT_FLOATS)   // A fragments: 64 steps * 8 frags * 64 lanes * 8 f16
#define AF_FLOATS (NSTEP * 4096 / 2)  // 131072 floats = 512KB
#define WS_FLOATS_TOTAL (AF_OFF + AF_FLOATS)

__device__ __forceinline__ float softplus_f(float x) {
    return (x > 0.f) ? (x + log1pf(expf(-x))) : log1pf(expf(x));
}

// split (x0,x1) into packed f16 hi (RTZ) + f16 lo (RTZ of remainder)
__device__ __forceinline__ void split_f16x2(float x0, float x1, unsigned& uh, unsigned& ul) {
    fp16x2 h = __builtin_amdgcn_cvt_pkrtz(x0, x1);
    float r0 = x0 - (float)h[0];
    float r1 = x1 - (float)h[1];
    fp16x2 lo = __builtin_amdgcn_cvt_pkrtz(r0, r1);
    uh = __builtin_bit_cast(unsigned, h);
    ul = __builtin_bit_cast(unsigned, lo);
}

// ---- K0: pack A (rows 0-31 = inputs, 32-63 = V[tgt]) into fragment-major f16 hi/lo ----
// layout (ushort idx): s*4096 + f*512 + lane*8 + j ; f = rb (hi) or 4+rb (lo)
__global__ __launch_bounds__(256) void build_Afrag(const float* __restrict__ in,
                                                   const float* __restrict__ V,
                                                   const int* __restrict__ tgt,
                                                   unsigned short* __restrict__ Af) {
    int s = blockIdx.x;           // 0..63
    int rb = threadIdx.x >> 6;    // 0..3
    int l = threadIdx.x & 63;
    int row = rb * 16 + (l & 15);
    int k = s * 32 + (l >> 4) * 8;
    const float* src = (row < 32) ? (in + (size_t)row * D_ + k)
                                  : (V + (size_t)tgt[row - 32] * D_ + k);
    f32x4 x0 = *(const f32x4*)src;
    f32x4 x1 = *(const f32x4*)(src + 4);
    unsigned uh0, ul0, uh1, ul1, uh2, ul2, uh3, ul3;
    split_f16x2(x0[0], x0[1], uh0, ul0);
    split_f16x2(x0[2], x0[3], uh1, ul1);
    split_f16x2(x1[0], x1[1], uh2, ul2);
    split_f16x2(x1[2], x1[3], uh3, ul3);
    size_t base = (size_t)s * 4096 + (size_t)l * 8;
    *(uint4*)(Af + base + rb * 512) = make_uint4(uh0, uh1, uh2, uh3);
    *(uint4*)(Af + base + (4 + rb) * 512) = make_uint4(ul0, ul1, ul2, ul3);
}

// ---- K1b: raw 32x32 batch dots ----
__global__ __launch_bounds__(256) void sims_dots(const float* __restrict__ in,
                                                 float* __restrict__ dt) {
    __shared__ float part[8][32];
    int i = blockIdx.x;
    int j = threadIdx.x & 31;
    int sl = threadIdx.x >> 5;
    const float4* a4 = (const float4*)(in + (size_t)i * D_ + sl * 256);
    const float4* b4 = (const float4*)(in + (size_t)j * D_ + sl * 256);
    float s = 0.f;
#pragma unroll 4
    for (int k = 0; k < 64; ++k) {
        float4 x = a4[k], y = b4[k];
        s += x.x * y.x + x.y * y.y + x.z * y.z + x.w * y.w;
    }
    part[sl][j] = s;
    __syncthreads();
    if (threadIdx.x < 32) {
        float t = 0.f;
#pragma unroll
        for (int p = 0; p < 8; ++p) t += part[p][threadIdx.x];
        dt[i * 32 + threadIdx.x] = t;
    }
}

// ---- K1c: sims, thresholds, h_loss, n_th_t ----
__global__ __launch_bounds__(1024) void small_finish(const float* __restrict__ in,
                                                     const float* __restrict__ V,
                                                     const int* __restrict__ tgt,
                                                     float* __restrict__ ws) {
    __shared__ float sims[32][33];
    __shared__ float nthr[32], pthr[32];
    __shared__ int ts[32];
    __shared__ float diag[32];
    __shared__ float red[4];
    int tid = threadIdx.x;
    int i = tid >> 5, j = tid & 31;
    const float* dt = ws + DT_OFF;
    if (tid < 32) { ts[tid] = tgt[tid]; diag[tid] = dt[tid * 32 + tid]; }
    if (tid < 4) red[tid] = 0.f;
    __syncthreads();
    float sim = dt[i * 32 + j] * rsqrtf(diag[i] * diag[j]);
    sims[i][j] = sim;
    __syncthreads();
    if (tid < 32) {
        float nmin = 2.f, pmax = -2.f;
        int ti = ts[tid];
        for (int jj = 0; jj < 32; ++jj) {
            bool pos = (ts[jj] == ti) && (jj != tid);
            float v = sims[tid][jj];
            if (pos) { nmin = fminf(nmin, v); pmax = fmaxf(pmax, v); }
        }
        nthr[tid] = nmin - N_MARG;
        pthr[tid] = pmax - P_MARG;
    }
    __syncthreads();
    bool pos = (ts[i] == ts[j]) && (i != j);
    bool neg = (ts[i] != ts[j]);
    if (pos && sim < pthr[i]) { atomicAdd(&red[0], softplus_f(-sim)); atomicAdd(&red[1], 1.f); }
    if (neg && sim > nthr[i]) { atomicAdd(&red[2], softplus_f(sim)); atomicAdd(&red[3], 1.f); }

    const float4* a4 = (const float4*)(in + (size_t)i * D_);
    const float4* v4 = (const float4*)(V + (size_t)ts[i] * D_);
    float sn = 0.f;
    for (int k = j; k < D_ / 4; k += 32) {
        float4 x = a4[k], y = v4[k];
        sn += x.x * y.x + x.y * y.y + x.z * y.z + x.w * y.w;
    }
    for (int off = 16; off > 0; off >>= 1) sn += __shfl_down(sn, off, 32);
    if (j == 0) ws[SC_OFF + S_NTH + i] = sn * rsqrtf(diag[i]) - N_MARG;
    __syncthreads();
    if (tid == 0) {
        float h = 0.f;
        if (red[1] > 0.f) h += red[0] / red[1];
        if (red[3] > 0.f) h += red[2] / red[3];
        ws[SC_OFF + S_HLOSS] = h;
    }
}

// ---- epilogue helpers ----
__device__ __forceinline__ void out_tile(f32x4 a, int rowbase, int g, int col, int n0,
                                         int wid, float* __restrict__ out,
                                         float* __restrict__ ws) {
#pragma unroll
    for (int r = 0; r < 4; ++r) {
        int row = rowbase + g * 4 + r;
        float y = a[r] * T_SCALE;
        out[(size_t)row * C_ + n0 + col] = y;
        float gm = y;
        gm = fmaxf(gm, __shfl_xor(gm, 1));
        gm = fmaxf(gm, __shfl_xor(gm, 2));
        gm = fmaxf(gm, __shfl_xor(gm, 4));
        gm = fmaxf(gm, __shfl_xor(gm, 8));
        float es = expf(y - gm);
        es += __shfl_xor(es, 1);
        es += __shfl_xor(es, 2);
        es += __shfl_xor(es, 4);
        es += __shfl_xor(es, 8);
        if (col == 0) {
            ws[PM_OFF + (size_t)row * NWAVE + wid] = gm;
            ws[PS_OFF + (size_t)row * NWAVE + wid] = es;
        }
    }
}

__device__ __forceinline__ void th_tile(f32x4 a, int bbase, int g, const float* __restrict__ nthp,
                                        float& ts, float& tc) {
#pragma unroll
    for (int r = 0; r < 4; ++r) {
        int b = bbase + g * 4 + r;
        float x = a[r];
        float nth = nthp[b];
        if (x > nth && x < 0.9999f) { ts += softplus_f(x); tc += 1.f; }
    }
}

// ---- K2: MFMA GEMM, triple-buffered counted-vmcnt pipeline (T4).
//      Block = 32 cols (2 waves x 16), LDS 36KB -> 4 blocks/CU, grid 1250.
//      Per step/wave: 6 GLL (4 A-frag + 2 V, swizzled source), 12 ds_read_b128,
//      12 MFMA. s_waitcnt vmcnt(6) + raw s_barrier: 2-steps-ahead stays in flight.
__global__ __launch_bounds__(128, 2) void gemm_mfma(const float* __restrict__ V,
                                                    const unsigned short* __restrict__ Af,
                                                    float* __restrict__ out,
                                                    float* __restrict__ ws) {
    __shared__ unsigned short A0s[8][512], A1s[8][512], A2s[8][512]; // 8KB each
    __shared__ float V0s[32][32], V1s[32][32], V2s[32][32];          // 4KB each
    const int l = threadIdx.x & 63;
    const int w = threadIdx.x >> 6; // 0..1
    const int wid = blockIdx.x * 2 + w;
    const int col = l & 15, g = l >> 4;
    const int n0blk = blockIdx.x * 32;
    const int n0 = wid * 16;

    f32x4 acc0 = {0.f, 0.f, 0.f, 0.f};
    f32x4 acc1 = acc0, acc2 = acc0, acc3 = acc0;
    float vsum = 0.f;

    // staging geometry: wave stages A frags 4w..4w+3 and its own 16 V rows
    const int vr0 = 16 * w + (l >> 3);            // block-local V row, first 8-row group
    const int vc0 = (((l & 7) ^ ((l >> 3) & 7)) * 4); // swizzled source float col
    const int vsw = (col & 7) << 2;               // read-side swizzle
    const int g8 = g * 8;

#define STAGE(Ab, Vb, t)                                                          \
    do {                                                                          \
        const size_t sa_ = (size_t)(t) * 4096;                                    \
        GLL(Af + sa_ + (size_t)(4 * w + 0) * 512 + l * 8, &Ab[4 * w + 0][0]);     \
        GLL(Af + sa_ + (size_t)(4 * w + 1) * 512 + l * 8, &Ab[4 * w + 1][0]);     \
        GLL(Af + sa_ + (size_t)(4 * w + 2) * 512 + l * 8, &Ab[4 * w + 2][0]);     \
        GLL(Af + sa_ + (size_t)(4 * w + 3) * 512 + l * 8, &Ab[4 * w + 3][0]);     \
        GLL(V + (size_t)(n0blk + vr0) * D_ + (size_t)(t) * 32 + vc0,              \
            &Vb[16 * w][0]);                                                      \
        GLL(V + (size_t)(n0blk + vr0 + 8) * D_ + (size_t)(t) * 32 + vc0,          \
            &Vb[16 * w + 8][0]);                                                  \
    } while (0)

#define COMPUTE(Ab, Vb)                                                            \
    do {                                                                           \
        uint4 a0 = *(const uint4*)&Ab[0][l * 8];                                   \
        uint4 a1 = *(const uint4*)&Ab[1][l * 8];                                   \
        uint4 a2 = *(const uint4*)&Ab[2][l * 8];                                   \
        uint4 a3 = *(const uint4*)&Ab[3][l * 8];                                   \
        uint4 a4 = *(const uint4*)&Ab[4][l * 8];                                   \
        uint4 a5 = *(const uint4*)&Ab[5][l * 8];                                   \
        uint4 a6 = *(const uint4*)&Ab[6][l * 8];                                   \
        uint4 a7 = *(const uint4*)&Ab[7][l * 8];                                   \
        f32x4 v0 = *(const f32x4*)&Vb[16 * w + col][g8 ^ vsw];                     \
        f32x4 v1 = *(const f32x4*)&Vb[16 * w + col][(g8 + 4) ^ vsw];               \
        vsum += v0[0] + v0[1] + v0[2] + v0[3] + v1[0] + v1[1] + v1[2] + v1[3];     \
        unsigned uh0, ul0, uh1, ul1, uh2, ul2, uh3, ul3;                           \
        split_f16x2(v0[0], v0[1], uh0, ul0);                                       \
        split_f16x2(v0[2], v0[3], uh1, ul1);                                       \
        split_f16x2(v1[0], v1[1], uh2, ul2);                                       \
        split_f16x2(v1[2], v1[3], uh3, ul3);                                       \
        half8_t bh = __builtin_bit_cast(half8_t, make_uint4(uh0, uh1, uh2, uh3));  \
        half8_t bl = __builtin_bit_cast(half8_t, make_uint4(ul0, ul1, ul2, ul3));  \
        half8_t a0h = __builtin_bit_cast(half8_t, a0);                             \
        half8_t a1h = __builtin_bit_cast(half8_t, a1);                             \
        half8_t a2h = __builtin_bit_cast(half8_t, a2);                             \
        half8_t a3h = __builtin_bit_cast(half8_t, a3);                             \
        half8_t a0l = __builtin_bit_cast(half8_t, a4);                             \
        half8_t a1l = __builtin_bit_cast(half8_t, a5);                             \
        half8_t a2l = __builtin_bit_cast(half8_t, a6);                             \
        half8_t a3l = __builtin_bit_cast(half8_t, a7);                             \
        acc0 = __builtin_amdgcn_mfma_f32_16x16x32_f16(a0h, bh, acc0, 0, 0, 0);     \
        acc1 = __builtin_amdgcn_mfma_f32_16x16x32_f16(a1h, bh, acc1, 0, 0, 0);     \
        acc2 = __builtin_amdgcn_mfma_f32_16x16x32_f16(a2h, bh, acc2, 0, 0, 0);     \
        acc3 = __builtin_amdgcn_mfma_f32_16x16x32_f16(a3h, bh, acc3, 0, 0, 0);     \
        acc0 = __builtin_amdgcn_mfma_f32_16x16x32_f16(a0h, bl, acc0, 0, 0, 0);     \
        acc1 = __builtin_amdgcn_mfma_f32_16x16x32_f16(a1h, bl, acc1, 0, 0, 0);     \
        acc2 = __builtin_amdgcn_mfma_f32_16x16x32_f16(a2h, bl, acc2, 0, 0, 0);     \
        acc3 = __builtin_amdgcn_mfma_f32_16x16x32_f16(a3h, bl, acc3, 0, 0, 0);     \
        acc0 = __builtin_amdgcn_mfma_f32_16x16x32_f16(a0l, bh, acc0, 0, 0, 0);     \
        acc1 = __builtin_amdgcn_mfma_f32_16x16x32_f16(a1l, bh, acc1, 0, 0, 0);     \
        acc2 = __builtin_amdgcn_mfma_f32_16x16x32_f16(a2l, bh, acc2, 0, 0, 0);     \
        acc3 = __builtin_amdgcn_mfma_f32_16x16x32_f16(a3l, bh, acc3, 0, 0, 0);     \
    } while (0)

#define SYNC(N)                                                       \
    do {                                                              \
        __builtin_amdgcn_sched_barrier(0);                            \
        asm volatile("s_waitcnt vmcnt(" #N ") lgkmcnt(0)" ::: "memory"); \
        __builtin_amdgcn_s_barrier();                                 \
        __builtin_amdgcn_sched_barrier(0);                            \
    } while (0)

    // prologue: stage steps 0,1
    STAGE(A0s, V0s, 0);
    STAGE(A1s, V1s, 1);
    SYNC(6); // step-0 batch landed (step-1 batch may be in flight)

    // main loop: steps 0..59 (20 x 3-unrolled); stage t+2 each step
    for (int t = 0; t < 60; t += 3) {
        STAGE(A2s, V2s, t + 2);
        COMPUTE(A0s, V0s);
        SYNC(6);
        STAGE(A0s, V0s, t + 3);
        COMPUTE(A1s, V1s);
        SYNC(6);
        STAGE(A1s, V1s, t + 4);
        COMPUTE(A2s, V2s);
        SYNC(6);
    }
    // tail: steps 60..63 (60->A0s, 61->A1s already staged)
    STAGE(A2s, V2s, 62);
    COMPUTE(A0s, V0s);
    SYNC(6);
    STAGE(A0s, V0s, 63);
    COMPUTE(A1s, V1s);
    SYNC(6);
    COMPUTE(A2s, V2s);
    SYNC(0);
    COMPUTE(A0s, V0s);

#undef STAGE
#undef COMPUTE
#undef SYNC

    // V row-sum zero check (full K, this wave's 16 cols)
    vsum += __shfl_xor(vsum, 16);
    vsum += __shfl_xor(vsum, 32);
    if (g == 0 && vsum == 0.0f) ws[SC_OFF + S_BAD] = 1.0f;

    // outputs rows 0..31 (+ lse partials)
    out_tile(acc0, 0, g, col, n0, wid, out, ws);
    out_tile(acc1, 16, g, col, n0, wid, out, ws);

    // th term from nsims accumulators (rows 32..63)
    float ts = 0.f, tc = 0.f;
    const float* nthp = ws + SC_OFF + S_NTH;
    th_tile(acc2, 0, g, nthp, ts, tc);
    th_tile(acc3, 16, g, nthp, ts, tc);
#pragma unroll
    for (int off = 32; off >= 1; off >>= 1) {
        ts += __shfl_xor(ts, off);
        tc += __shfl_xor(tc, off);
    }
    if (l == 0 && tc != 0.f) {
        atomicAdd(&ws[SC_OFF + S_THSUM], ts);
        atomicAdd(&ws[SC_OFF + S_THCNT], tc);
    }
}

// ---- K3: combine lse partials, bu term ----
__global__ __launch_bounds__(256) void lse_combine(const float* __restrict__ out,
                                                   const int* __restrict__ tgt,
                                                   float* __restrict__ ws) {
    int b = blockIdx.x;
    int tid = threadIdx.x;
    __shared__ float sm[256];
    const float* pm = ws + PM_OFF + (size_t)b * NWAVE;
    const float* ps = ws + PS_OFF + (size_t)b * NWAVE;
    float m = -INFINITY;
    for (int i = tid; i < NWAVE; i += 256) m = fmaxf(m, pm[i]);
    sm[tid] = m;
    __syncthreads();
    for (int s = 128; s > 0; s >>= 1) {
        if (tid < s) sm[tid] = fmaxf(sm[tid], sm[tid + s]);
        __syncthreads();
    }
    float M = sm[0];
    __syncthreads();
    float s = 0.f;
    for (int i = tid; i < NWAVE; i += 256) s += ps[i] * expf(pm[i] - M);
    sm[tid] = s;
    __syncthreads();
    for (int st = 128; st > 0; st >>= 1) {
        if (tid < st) sm[tid] += sm[tid + st];
        __syncthreads();
    }
    if (tid == 0) {
        float lse = M + logf(sm[0]);
        ws[SC_OFF + S_BU + b] = lse - out[(size_t)b * C_ + tgt[b]];
    }
}

// ---- K5: combine ----
__global__ void finalize(const float* __restrict__ ws, float* __restrict__ out0) {
    if (threadIdx.x == 0 && blockIdx.x == 0) {
        float bu = 0.f;
        for (int b = 0; b < 32; ++b) bu += ws[SC_OFF + S_BU + b];
        bu /= 32.f;
        float h = ws[SC_OFF + S_HLOSS];
        float th = 0.f;
        float cnt = ws[SC_OFF + S_THCNT];
        if (ws[SC_OFF + S_BAD] == 0.f && cnt > 0.f) th = ws[SC_OFF + S_THSUM] / cnt;
        out0[0] = 1.0f * bu + 1.0f * h + 3.0f * th;
    }
}

extern "C" void kernel_launch(void* const* d_in, const int* in_sizes, int n_in,
                              void* d_out, int out_size, void* d_ws, size_t ws_size,
                              hipStream_t stream) {
    const float* in = (const float*)d_in[0];
    const float* V = (const float*)d_in[1];
    const int* tgt = (const int*)d_in[2];
    float* outp = (float*)d_out;
    float* ws = (float*)d_ws;
    unsigned short* Af = (unsigned short*)(ws + AF_OFF);

    (void)hipMemsetAsync((void*)(ws + SC_OFF), 0, SC_FLOATS * sizeof(float), stream);

    build_Afrag<<<NSTEP, 256, 0, stream>>>(in, V, tgt, Af);
    sims_dots<<<32, 256, 0, stream>>>(in, ws + DT_OFF);
    small_finish<<<1, 1024, 0, stream>>>(in, V, tgt, ws);

    gemm_mfma<<<NBLK2, 128, 0, stream>>>(V, Af, outp + 1, ws);

    lse_combine<<<B_, 256, 0, stream>>>(outp + 1, tgt, ws);
    finalize<<<1, 64, 0, stream>>>(ws, outp);
}

// Round 11
// 195.451 us; speedup vs baseline: 1.3400x; 1.3400x over previous
//
#include <hip/hip_runtime.h>
#include <math.h>

#define B_ 32
#define C_ 40000
#define D_ 2048
#define T_SCALE 10.0f
#define P_MARG 0.2f
#define N_MARG 0.3f
#define NWAVE (C_ / 16)  // 2500 col-groups of 16 (PM/PS stride)
#define NBLK (C_ / 64)   // 625 blocks (2 waves x 2 col-groups)
#define NSTEP (D_ / 32)  // 64 k-steps of K=32

typedef __attribute__((ext_vector_type(4))) float f32x4;
typedef __fp16 fp16x2 __attribute__((ext_vector_type(2)));
typedef _Float16 f16x2n __attribute__((ext_vector_type(2)));
typedef _Float16 half8_t __attribute__((ext_vector_type(8)));

// async global->LDS, 16B per lane; LDS dest = wave-uniform base + lane*16
#define GLL(gsrc, ldst)                                                          \
    __builtin_amdgcn_global_load_lds(                                            \
        (const __attribute__((address_space(1))) unsigned int*)(gsrc),           \
        (__attribute__((address_space(3))) unsigned int*)(ldst), 16, 0, 0)

// ---- workspace layout (in floats) ----
#define PM_OFF 0                      // pmax [32][NWAVE]
#define PM_FLOATS (B_ * NWAVE)
#define PS_OFF (PM_OFF + PM_FLOATS)   // psum [32][NWAVE]
#define PS_FLOATS (B_ * NWAVE)
#define SC_OFF (PS_OFF + PS_FLOATS)   // scalars
#define S_HLOSS 0
#define S_THSUM 1
#define S_THCNT 2
#define S_BAD 3
#define S_NTH 4  // 32 floats
#define S_BU 36  // 32 floats
#define SC_FLOATS 128
#define DT_OFF (SC_OFF + SC_FLOATS)   // raw batch dots [32][32]
#define DT_FLOATS (32 * 32)
#define AF_OFF (DT_OFF + DT_FLOATS)   // A fragments (f16 hi only): 64 steps * 4 frags * 64 lanes * 8
#define AF_FLOATS (NSTEP * 2048 / 2)  // 65536 ushorts = 32768 floats = 256KB
#define WS_FLOATS_TOTAL (AF_OFF + AF_FLOATS)

__device__ __forceinline__ float softplus_f(float x) {
    return (x > 0.f) ? (x + log1pf(expf(-x))) : log1pf(expf(x));
}

// split (x0,x1) into packed f16 hi (RTZ) + f16 lo (RTZ of remainder)
__device__ __forceinline__ void split_f16x2(float x0, float x1, unsigned& uh, unsigned& ul) {
    fp16x2 h = __builtin_amdgcn_cvt_pkrtz(x0, x1);
    float r0 = x0 - (float)h[0];
    float r1 = x1 - (float)h[1];
    fp16x2 lo = __builtin_amdgcn_cvt_pkrtz(r0, r1);
    uh = __builtin_bit_cast(unsigned, h);
    ul = __builtin_bit_cast(unsigned, lo);
}

// pack 2 floats to f16x2 with RTNE (default cast rounding)
__device__ __forceinline__ unsigned pack_rtne(float x0, float x1) {
    f16x2n p = {(_Float16)x0, (_Float16)x1};
    return __builtin_bit_cast(unsigned, p);
}

// ---- K0: pack A (rows 0-31 = inputs, 32-63 = V[tgt]) fragment-major, f16 hi only ----
// layout (ushort idx): s*2048 + f*512 + lane*8 + j ; f = 0..3 (16 rows each)
__global__ __launch_bounds__(256) void build_Afrag(const float* __restrict__ in,
                                                   const float* __restrict__ V,
                                                   const int* __restrict__ tgt,
                                                   unsigned short* __restrict__ Af) {
    int s = blockIdx.x;           // 0..63
    int f = threadIdx.x >> 6;     // 0..3
    int l = threadIdx.x & 63;
    int row = f * 16 + (l & 15);
    int k = s * 32 + (l >> 4) * 8;
    const float* src = (row < 32) ? (in + (size_t)row * D_ + k)
                                  : (V + (size_t)tgt[row - 32] * D_ + k);
    f32x4 x0 = *(const f32x4*)src;
    f32x4 x1 = *(const f32x4*)(src + 4);
    uint4 u = make_uint4(pack_rtne(x0[0], x0[1]), pack_rtne(x0[2], x0[3]),
                         pack_rtne(x1[0], x1[1]), pack_rtne(x1[2], x1[3]));
    *(uint4*)(Af + (size_t)s * 2048 + (size_t)f * 512 + (size_t)l * 8) = u;
}

// ---- K1b: raw 32x32 batch dots ----
__global__ __launch_bounds__(256) void sims_dots(const float* __restrict__ in,
                                                 float* __restrict__ dt) {
    __shared__ float part[8][32];
    int i = blockIdx.x;
    int j = threadIdx.x & 31;
    int sl = threadIdx.x >> 5;
    const float4* a4 = (const float4*)(in + (size_t)i * D_ + sl * 256);
    const float4* b4 = (const float4*)(in + (size_t)j * D_ + sl * 256);
    float s = 0.f;
#pragma unroll 4
    for (int k = 0; k < 64; ++k) {
        float4 x = a4[k], y = b4[k];
        s += x.x * y.x + x.y * y.y + x.z * y.z + x.w * y.w;
    }
    part[sl][j] = s;
    __syncthreads();
    if (threadIdx.x < 32) {
        float t = 0.f;
#pragma unroll
        for (int p = 0; p < 8; ++p) t += part[p][threadIdx.x];
        dt[i * 32 + threadIdx.x] = t;
    }
}

// ---- K1c: sims, thresholds, h_loss, n_th_t ----
__global__ __launch_bounds__(1024) void small_finish(const float* __restrict__ in,
                                                     const float* __restrict__ V,
                                                     const int* __restrict__ tgt,
                                                     float* __restrict__ ws) {
    __shared__ float sims[32][33];
    __shared__ float nthr[32], pthr[32];
    __shared__ int ts[32];
    __shared__ float diag[32];
    __shared__ float red[4];
    int tid = threadIdx.x;
    int i = tid >> 5, j = tid & 31;
    const float* dt = ws + DT_OFF;
    if (tid < 32) { ts[tid] = tgt[tid]; diag[tid] = dt[tid * 32 + tid]; }
    if (tid < 4) red[tid] = 0.f;
    __syncthreads();
    float sim = dt[i * 32 + j] * rsqrtf(diag[i] * diag[j]);
    sims[i][j] = sim;
    __syncthreads();
    if (tid < 32) {
        float nmin = 2.f, pmax = -2.f;
        int ti = ts[tid];
        for (int jj = 0; jj < 32; ++jj) {
            bool pos = (ts[jj] == ti) && (jj != tid);
            float v = sims[tid][jj];
            if (pos) { nmin = fminf(nmin, v); pmax = fmaxf(pmax, v); }
        }
        nthr[tid] = nmin - N_MARG;
        pthr[tid] = pmax - P_MARG;
    }
    __syncthreads();
    bool pos = (ts[i] == ts[j]) && (i != j);
    bool neg = (ts[i] != ts[j]);
    if (pos && sim < pthr[i]) { atomicAdd(&red[0], softplus_f(-sim)); atomicAdd(&red[1], 1.f); }
    if (neg && sim > nthr[i]) { atomicAdd(&red[2], softplus_f(sim)); atomicAdd(&red[3], 1.f); }

    const float4* a4 = (const float4*)(in + (size_t)i * D_);
    const float4* v4 = (const float4*)(V + (size_t)ts[i] * D_);
    float sn = 0.f;
    for (int k = j; k < D_ / 4; k += 32) {
        float4 x = a4[k], y = v4[k];
        sn += x.x * y.x + x.y * y.y + x.z * y.z + x.w * y.w;
    }
    for (int off = 16; off > 0; off >>= 1) sn += __shfl_down(sn, off, 32);
    if (j == 0) ws[SC_OFF + S_NTH + i] = sn * rsqrtf(diag[i]) - N_MARG;
    __syncthreads();
    if (tid == 0) {
        float h = 0.f;
        if (red[1] > 0.f) h += red[0] / red[1];
        if (red[3] > 0.f) h += red[2] / red[3];
        ws[SC_OFF + S_HLOSS] = h;
    }
}

// ---- epilogue helpers ----
__device__ __forceinline__ void out_tile(f32x4 a, int rowbase, int g, int col, int n0,
                                         int wid, float* __restrict__ out,
                                         float* __restrict__ ws) {
#pragma unroll
    for (int r = 0; r < 4; ++r) {
        int row = rowbase + g * 4 + r;
        float y = a[r] * T_SCALE;
        out[(size_t)row * C_ + n0 + col] = y;
        float gm = y;
        gm = fmaxf(gm, __shfl_xor(gm, 1));
        gm = fmaxf(gm, __shfl_xor(gm, 2));
        gm = fmaxf(gm, __shfl_xor(gm, 4));
        gm = fmaxf(gm, __shfl_xor(gm, 8));
        float es = expf(y - gm);
        es += __shfl_xor(es, 1);
        es += __shfl_xor(es, 2);
        es += __shfl_xor(es, 4);
        es += __shfl_xor(es, 8);
        if (col == 0) {
            ws[PM_OFF + (size_t)row * NWAVE + wid] = gm;
            ws[PS_OFF + (size_t)row * NWAVE + wid] = es;
        }
    }
}

__device__ __forceinline__ void th_tile(f32x4 a, int bbase, int g, const float* __restrict__ nthp,
                                        float& ts, float& tc) {
#pragma unroll
    for (int r = 0; r < 4; ++r) {
        int b = bbase + g * 4 + r;
        float x = a[r];
        float nth = nthp[b];
        if (x > nth && x < 0.9999f) { ts += softplus_f(x); tc += 1.f; }
    }
}

// ---- K2: MFMA GEMM, 3-buffer counted-vmcnt pipeline.
//      Block = 64 cols (2 waves x 2 col-groups of 16). A = single f16 (4KB/step),
//      V = f32 staged (8KB/step), split to f16 hi/lo in-regs. 16 MFMA/wave/step.
//      LDS 36KB. Per wave/step: 6 GLL; vmcnt(6) keeps next batch in flight.
__global__ __launch_bounds__(128, 2) void gemm_mfma(const float* __restrict__ V,
                                                    const unsigned short* __restrict__ Af,
                                                    float* __restrict__ out,
                                                    float* __restrict__ ws) {
    __shared__ unsigned short A0s[4][512], A1s[4][512], A2s[4][512]; // 4KB each
    __shared__ float V0s[64][32], V1s[64][32], V2s[64][32];          // 8KB each
    const int l = threadIdx.x & 63;
    const int w = threadIdx.x >> 6; // 0..1
    const int col = l & 15, g = l >> 4;
    const int n0blk = blockIdx.x * 64;

    f32x4 z = {0.f, 0.f, 0.f, 0.f};
    f32x4 acc00 = z, acc01 = z, acc02 = z, acc03 = z; // col-group 0
    f32x4 acc10 = z, acc11 = z, acc12 = z, acc13 = z; // col-group 1
    float vs0 = 0.f, vs1 = 0.f;

    const int vr = l >> 3;                 // 0..7
    const int vc0 = ((l & 7) ^ vr) * 4;    // swizzled source float col
    const int vsw = (col & 7) << 2;        // read-side swizzle
    const int g8 = g * 8;

#define STAGE(Ab, Vb, t)                                                         \
    do {                                                                         \
        const size_t sa_ = (size_t)(t) * 2048;                                   \
        GLL(Af + sa_ + (size_t)(2 * w + 0) * 512 + l * 8, &Ab[2 * w + 0][0]);    \
        GLL(Af + sa_ + (size_t)(2 * w + 1) * 512 + l * 8, &Ab[2 * w + 1][0]);    \
        const size_t sv_ = (size_t)(t) * 32 + vc0;                               \
        GLL(V + (size_t)(n0blk + 32 * w + vr) * D_ + sv_, &Vb[32 * w][0]);       \
        GLL(V + (size_t)(n0blk + 32 * w + 8 + vr) * D_ + sv_, &Vb[32 * w + 8][0]);   \
        GLL(V + (size_t)(n0blk + 32 * w + 16 + vr) * D_ + sv_, &Vb[32 * w + 16][0]); \
        GLL(V + (size_t)(n0blk + 32 * w + 24 + vr) * D_ + sv_, &Vb[32 * w + 24][0]); \
    } while (0)

#define CGROUP(Vb, r, accA, accB, accC, accD, vsx)                                 \
    do {                                                                           \
        f32x4 v0 = *(const f32x4*)&Vb[r][g8 ^ vsw];                                \
        f32x4 v1 = *(const f32x4*)&Vb[r][(g8 + 4) ^ vsw];                          \
        vsx += v0[0] + v0[1] + v0[2] + v0[3] + v1[0] + v1[1] + v1[2] + v1[3];      \
        unsigned uh0, ul0, uh1, ul1, uh2, ul2, uh3, ul3;                           \
        split_f16x2(v0[0], v0[1], uh0, ul0);                                       \
        split_f16x2(v0[2], v0[3], uh1, ul1);                                       \
        split_f16x2(v1[0], v1[1], uh2, ul2);                                       \
        split_f16x2(v1[2], v1[3], uh3, ul3);                                       \
        half8_t bh = __builtin_bit_cast(half8_t, make_uint4(uh0, uh1, uh2, uh3));  \
        half8_t bl = __builtin_bit_cast(half8_t, make_uint4(ul0, ul1, ul2, ul3));  \
        accA = __builtin_amdgcn_mfma_f32_16x16x32_f16(A0h, bh, accA, 0, 0, 0);     \
        accB = __builtin_amdgcn_mfma_f32_16x16x32_f16(A1h, bh, accB, 0, 0, 0);     \
        accC = __builtin_amdgcn_mfma_f32_16x16x32_f16(A2h, bh, accC, 0, 0, 0);     \
        accD = __builtin_amdgcn_mfma_f32_16x16x32_f16(A3h, bh, accD, 0, 0, 0);     \
        accA = __builtin_amdgcn_mfma_f32_16x16x32_f16(A0h, bl, accA, 0, 0, 0);     \
        accB = __builtin_amdgcn_mfma_f32_16x16x32_f16(A1h, bl, accB, 0, 0, 0);     \
        accC = __builtin_amdgcn_mfma_f32_16x16x32_f16(A2h, bl, accC, 0, 0, 0);     \
        accD = __builtin_amdgcn_mfma_f32_16x16x32_f16(A3h, bl, accD, 0, 0, 0);     \
    } while (0)

#define COMPUTE(Ab, Vb)                                                       \
    do {                                                                      \
        uint4 a0 = *(const uint4*)&Ab[0][l * 8];                              \
        uint4 a1 = *(const uint4*)&Ab[1][l * 8];                              \
        uint4 a2 = *(const uint4*)&Ab[2][l * 8];                              \
        uint4 a3 = *(const uint4*)&Ab[3][l * 8];                              \
        half8_t A0h = __builtin_bit_cast(half8_t, a0);                        \
        half8_t A1h = __builtin_bit_cast(half8_t, a1);                        \
        half8_t A2h = __builtin_bit_cast(half8_t, a2);                        \
        half8_t A3h = __builtin_bit_cast(half8_t, a3);                        \
        CGROUP(Vb, 32 * w + col, acc00, acc01, acc02, acc03, vs0);            \
        CGROUP(Vb, 32 * w + 16 + col, acc10, acc11, acc12, acc13, vs1);       \
    } while (0)

#define SYNC(N)                                                          \
    do {                                                                 \
        __builtin_amdgcn_sched_barrier(0);                               \
        asm volatile("s_waitcnt vmcnt(" #N ") lgkmcnt(0)" ::: "memory"); \
        __builtin_amdgcn_s_barrier();                                    \
        __builtin_amdgcn_sched_barrier(0);                               \
    } while (0)

    // prologue: stage steps 0,1
    STAGE(A0s, V0s, 0);
    STAGE(A1s, V1s, 1);
    SYNC(6); // step-0 batch landed (step-1 batch may be in flight)

    // main loop: steps 0..59 (20 x 3-unrolled); stage t+2 each step
    for (int t = 0; t < 60; t += 3) {
        STAGE(A2s, V2s, t + 2);
        COMPUTE(A0s, V0s);
        SYNC(6);
        STAGE(A0s, V0s, t + 3);
        COMPUTE(A1s, V1s);
        SYNC(6);
        STAGE(A1s, V1s, t + 4);
        COMPUTE(A2s, V2s);
        SYNC(6);
    }
    // tail: steps 60..63 (60->A0s, 61->A1s already staged)
    STAGE(A2s, V2s, 62);
    COMPUTE(A0s, V0s);
    SYNC(6);
    STAGE(A0s, V0s, 63);
    COMPUTE(A1s, V1s);
    SYNC(6);
    COMPUTE(A2s, V2s);
    SYNC(0);
    COMPUTE(A0s, V0s);

#undef STAGE
#undef CGROUP
#undef COMPUTE
#undef SYNC

    // V row-sum zero checks (full K) for this wave's 32 rows
    vs0 += __shfl_xor(vs0, 16);
    vs0 += __shfl_xor(vs0, 32);
    vs1 += __shfl_xor(vs1, 16);
    vs1 += __shfl_xor(vs1, 32);
    if (g == 0) {
        if (vs0 == 0.0f) ws[SC_OFF + S_BAD] = 1.0f;
        if (vs1 == 0.0f) ws[SC_OFF + S_BAD] = 1.0f;
    }

    const float* nthp = ws + SC_OFF + S_NTH;
    float ts = 0.f, tc = 0.f;
    // col-group 0
    {
        const int wid = blockIdx.x * 4 + 2 * w;
        const int n0 = n0blk + 32 * w;
        out_tile(acc00, 0, g, col, n0, wid, out, ws);
        out_tile(acc01, 16, g, col, n0, wid, out, ws);
        th_tile(acc02, 0, g, nthp, ts, tc);
        th_tile(acc03, 16, g, nthp, ts, tc);
    }
    // col-group 1
    {
        const int wid = blockIdx.x * 4 + 2 * w + 1;
        const int n0 = n0blk + 32 * w + 16;
        out_tile(acc10, 0, g, col, n0, wid, out, ws);
        out_tile(acc11, 16, g, col, n0, wid, out, ws);
        th_tile(acc12, 0, g, nthp, ts, tc);
        th_tile(acc13, 16, g, nthp, ts, tc);
    }
#pragma unroll
    for (int off = 32; off >= 1; off >>= 1) {
        ts += __shfl_xor(ts, off);
        tc += __shfl_xor(tc, off);
    }
    if (l == 0 && tc != 0.f) {
        atomicAdd(&ws[SC_OFF + S_THSUM], ts);
        atomicAdd(&ws[SC_OFF + S_THCNT], tc);
    }
}

// ---- K3: combine lse partials, bu term ----
__global__ __launch_bounds__(256) void lse_combine(const float* __restrict__ out,
                                                   const int* __restrict__ tgt,
                                                   float* __restrict__ ws) {
    int b = blockIdx.x;
    int tid = threadIdx.x;
    __shared__ float sm[256];
    const float* pm = ws + PM_OFF + (size_t)b * NWAVE;
    const float* ps = ws + PS_OFF + (size_t)b * NWAVE;
    float m = -INFINITY;
    for (int i = tid; i < NWAVE; i += 256) m = fmaxf(m, pm[i]);
    sm[tid] = m;
    __syncthreads();
    for (int s = 128; s > 0; s >>= 1) {
        if (tid < s) sm[tid] = fmaxf(sm[tid], sm[tid + s]);
        __syncthreads();
    }
    float M = sm[0];
    __syncthreads();
    float s = 0.f;
    for (int i = tid; i < NWAVE; i += 256) s += ps[i] * expf(pm[i] - M);
    sm[tid] = s;
    __syncthreads();
    for (int st = 128; st > 0; st >>= 1) {
        if (tid < st) sm[tid] += sm[tid + st];
        __syncthreads();
    }
    if (tid == 0) {
        float lse = M + logf(sm[0]);
        ws[SC_OFF + S_BU + b] = lse - out[(size_t)b * C_ + tgt[b]];
    }
}

// ---- K5: combine ----
__global__ void finalize(const float* __restrict__ ws, float* __restrict__ out0) {
    if (threadIdx.x == 0 && blockIdx.x == 0) {
        float bu = 0.f;
        for (int b = 0; b < 32; ++b) bu += ws[SC_OFF + S_BU + b];
        bu /= 32.f;
        float h = ws[SC_OFF + S_HLOSS];
        float th = 0.f;
        float cnt = ws[SC_OFF + S_THCNT];
        if (ws[SC_OFF + S_BAD] == 0.f && cnt > 0.f) th = ws[SC_OFF + S_THSUM] / cnt;
        out0[0] = 1.0f * bu + 1.0f * h + 3.0f * th;
    }
}

extern "C" void kernel_launch(void* const* d_in, const int* in_sizes, int n_in,
                              void* d_out, int out_size, void* d_ws, size_t ws_size,
                              hipStream_t stream) {
    const float* in = (const float*)d_in[0];
    const float* V = (const float*)d_in[1];
    const int* tgt = (const int*)d_in[2];
    float* outp = (float*)d_out;
    float* ws = (float*)d_ws;
    unsigned short* Af = (unsigned short*)(ws + AF_OFF);

    (void)hipMemsetAsync((void*)(ws + SC_OFF), 0, SC_FLOATS * sizeof(float), stream);

    build_Afrag<<<NSTEP, 256, 0, stream>>>(in, V, tgt, Af);
    sims_dots<<<32, 256, 0, stream>>>(in, ws + DT_OFF);
    small_finish<<<1, 1024, 0, stream>>>(in, V, tgt, ws);

    gemm_mfma<<<NBLK, 128, 0, stream>>>(V, Af, outp + 1, ws);

    lse_combine<<<B_, 256, 0, stream>>>(outp + 1, tgt, ws);
    finalize<<<1, 64, 0, stream>>>(ws, outp);
}